// Round 6
// baseline (845.419 us; speedup 1.0000x reference)
//
#include <hip/hip_runtime.h>
#include <math.h>

#define B_ 2
#define L_ 2048
#define DMODEL 2048
#define DINNER 4096
#define DSTATE 16
#define DCONV 4
#define DTRANK 128
#define NCHUNK 32
#define CLEN 64           // L_/NCHUNK
#define MROWS 4096        // B_*L_

typedef unsigned short ushort_t;
typedef unsigned int uint_t;
typedef __attribute__((ext_vector_type(8))) short bf16x8;
typedef __attribute__((ext_vector_type(4))) float floatx4;

__device__ __forceinline__ float sigmoidf_(float x){ return 1.f/(1.f+__expf(-x)); }
__device__ __forceinline__ ushort_t f2bf(float f){
    uint_t u = __builtin_bit_cast(uint_t, f);
    return (ushort_t)((u + 0x7FFFu + ((u >> 16) & 1u)) >> 16);
}
__device__ __forceinline__ float bf2f(ushort_t h){
    return __builtin_bit_cast(float, (uint_t)h << 16);
}
__device__ __forceinline__ float fast_exp2(float x){
#if __has_builtin(__builtin_amdgcn_exp2f)
    return __builtin_amdgcn_exp2f(x);
#else
    return exp2f(x);
#endif
}
#define LOG2E 1.44269504088896f

#define GLD_LDS16(g, l) __builtin_amdgcn_global_load_lds( \
    (const __attribute__((address_space(1))) void*)(g),   \
    (__attribute__((address_space(3))) void*)(l), 16, 0, 0)

// ---------------------------------------------------------------------------
// 128x128 bf16 MFMA GEMM (m97 structure) — used for x_proj (split-K, N=256),
// dt_proj (K=128), out_proj (N=2048 -> 512 blocks fill the machine).
// ---------------------------------------------------------------------------
template<int OUTBF, int EPI, int SPLIT, int KSPLIT>
__global__ __launch_bounds__(256)
void gemm_mfma(const ushort_t* __restrict__ Aptr, int lda,
               const ushort_t* __restrict__ W, int ldw,
               void* __restrict__ Cptr, void* __restrict__ C2,
               int ldc, int Klen,
               const float* __restrict__ bias)
{
    __shared__ ushort_t lsA[128*64];
    __shared__ ushort_t lsW[128*64];
    const int tid  = threadIdx.x;
    const int row0 = blockIdx.x * 128;
    const int col0 = blockIdx.y * 128;
    const int koff = KSPLIT ? blockIdx.z * Klen : 0;
    const int lane = tid & 63;
    const int wv   = tid >> 6;
    const int wm   = (wv >> 1) * 64;
    const int wn   = (wv & 1) * 64;
    const int lr   = lane & 15;
    const int lq   = lane >> 4;

    floatx4 acc[4][4];
    #pragma unroll
    for(int i=0;i<4;i++)
        #pragma unroll
        for(int j=0;j<4;j++)
            #pragma unroll
            for(int r=0;r<4;r++) acc[i][j][r] = 0.f;

    for(int k0 = koff; k0 < koff + Klen; k0 += 64){
        #pragma unroll
        for(int it=0; it<4; it++){
            const int slot = it*256 + tid;
            const int row  = slot >> 3;
            const int p    = slot & 7;
            const int s    = p ^ (row & 7);
            const ushort_t* gw = W    + (size_t)(col0 + row)*ldw + k0 + s*8;
            const ushort_t* ga = Aptr + (size_t)(row0 + row)*lda + k0 + s*8;
            GLD_LDS16(gw, &lsW[slot*8]);
            GLD_LDS16(ga, &lsA[slot*8]);
        }
        __syncthreads();

        #pragma unroll
        for(int kk=0; kk<2; kk++){
            bf16x8 af[4], bw[4];
            #pragma unroll
            for(int i=0;i<4;i++){
                const int ra = wm + i*16 + lr;
                const int rb = wn + i*16 + lr;
                af[i] = *(const bf16x8*)&lsA[ra*64 + (((kk*4+lq) ^ (ra&7))*8)];
                bw[i] = *(const bf16x8*)&lsW[rb*64 + (((kk*4+lq) ^ (rb&7))*8)];
            }
            #pragma unroll
            for(int i=0;i<4;i++)
                #pragma unroll
                for(int j=0;j<4;j++)
                    acc[i][j] = __builtin_amdgcn_mfma_f32_16x16x32_bf16(af[i], bw[j], acc[i][j], 0, 0, 0);
        }
        __syncthreads();
    }

    void* dst = Cptr;
    int cbase = col0;
    if (SPLIT && col0 >= ldc){ dst = C2; cbase = col0 - ldc; }
    const size_t zoff = KSPLIT ? (size_t)blockIdx.z * MROWS * ldc : 0;

    #pragma unroll
    for(int i=0;i<4;i++){
        #pragma unroll
        for(int r=0;r<4;r++){
            const int row = row0 + wm + i*16 + lq*4 + r;
            #pragma unroll
            for(int j=0;j<4;j++){
                const int col = cbase + wn + j*16 + lr;
                float v = acc[i][j][r];
                if (EPI){
                    v += bias[col];
                    v = (v > 20.f) ? v : log1pf(expf(v));
                }
                if (OUTBF) ((ushort_t*)dst)[(size_t)row*ldc + col] = f2bf(v);
                else       ((float*)  dst)[zoff + (size_t)row*ldc + col] = v;
            }
        }
    }
}

// ---------------------------------------------------------------------------
// 256x256 bf16 GEMM v6 (pipelined wide): C[M,N]=A[M,K]*W[N,K]^T.
// 1024 thr = 16 waves (4M x 4N), per-wave 64x64, BK=32, 4 waves/SIMD.
// LDS 128 KiB = lds[4][2][256x32] (4-deep tile rotation), 1 block/CU.
// v6 schedule — intra-wave software pipeline (R5 post-mortem: 4 waves/SIMD
// alone didn't overlap LDS with MFMA because the per-tile barrier kept all
// waves in the same phase; wall = LDS + MFMA serialized = 2340 cyc/tile):
//   body t:
//     vmcnt(2); s_barrier;       // tile t+1 landed (STG'd at body t-2,
//                                //  ~2 tiles = 3000 cyc ago >> 900 HBM lat)
//     8 ds_read frags(t+1) -> reg set (t+1)&1   [from buf (t+1)&3]
//     STG tile t+3 -> buf (t+3)&3               [== buf (t-1)&3, see WAR]
//     sched_barrier(0);          // pin reads above MFMAs
//     16 MFMA on reg set t&1     // compiler emits counted lgkmcnt(8):
//                                //  t's frags done, t+1's 8 reads in flight
//                                //  -> t+1 reads drain UNDER MFMA(t)
//   WAR: buf (t-1)&3 was read by frags(t-1) issued at body t-2 and
//   lgkm-drained before MFMA(t-1) in body t-1, which precedes this body's
//   barrier for every wave. Two frag reg sets hand-unrolled x2 (rule #20:
//   no runtime-indexed ext_vector arrays). Requires NT even, NT >= 4.
// Swizzle unchanged (0 conflicts measured): chunk c of row r at slot
// c ^ ((r>>1)&3); linear gload_lds dest, pre-swizzled per-lane source.
// ---------------------------------------------------------------------------
template<int OUTBF, int SPLIT>
__global__ __launch_bounds__(1024, 4)
void gemm_256w(const ushort_t* __restrict__ Aptr, int lda,
               const ushort_t* __restrict__ W, int ldw,
               void* __restrict__ Cptr, void* __restrict__ C2,
               int ldc, int Klen)
{
    __shared__ ushort_t lds[4][2][8192];   // [buf][A/W][256 rows x 32]
    const int tid  = threadIdx.x;
    const int row0 = blockIdx.x * 256;
    const int col0 = blockIdx.y * 256;
    const int koff = 0;
    const int NT   = Klen >> 5;            // K-tile = 32
    const int lane = tid & 63;
    const int wv   = tid >> 6;             // 0..15
    const int wr   = wv >> 2;              // 0..3 : M quarter (64 rows)
    const int wc   = wv & 3;               // 0..3 : N quarter (64 cols)
    const int lr   = lane & 15;
    const int lq   = lane >> 4;            // 0..3 : 16B chunk within row

    // staging: thread tid covers (row = tid>>2, slot p = tid&3);
    // source chunk c = p ^ ((row>>1)&3); dest linear tid*16B.
    const int srow = tid >> 2;
    const int sc   = (tid & 3) ^ ((srow >> 1) & 3);
    const ushort_t* aS = Aptr + (size_t)(row0 + srow)*lda + sc*8;
    const ushort_t* wS = W    + (size_t)(col0 + srow)*ldw + sc*8;
    const int sdst = tid*8;

    // ds_read bases (ushort units): frag i at base + i*512 (16 rows x 32)
    const int rA = wr*64 + lr;
    const int rB = wc*64 + lr;
    const int aA = rA*32 + ((lq ^ ((rA>>1)&3))*8);
    const int aB = rB*32 + ((lq ^ ((rB>>1)&3))*8);

    floatx4 acc[4][4];
    #pragma unroll
    for(int i=0;i<4;i++)
        #pragma unroll
        for(int j=0;j<4;j++)
            #pragma unroll
            for(int r=0;r<4;r++) acc[i][j][r] = 0.f;

    bf16x8 fa0[4], fb0[4], fa1[4], fb1[4];

    // prologue: stage tiles 0,1,2; wait tile 0; read frags(0) -> set 0
    GLD_LDS16(aS + koff,      &lds[0][0][sdst]);
    GLD_LDS16(wS + koff,      &lds[0][1][sdst]);
    GLD_LDS16(aS + koff + 32, &lds[1][0][sdst]);
    GLD_LDS16(wS + koff + 32, &lds[1][1][sdst]);
    GLD_LDS16(aS + koff + 64, &lds[2][0][sdst]);
    GLD_LDS16(wS + koff + 64, &lds[2][1][sdst]);
    asm volatile("s_waitcnt vmcnt(4)\ns_barrier" ::: "memory");
    #pragma unroll
    for(int j=0;j<4;j++) fb0[j] = *(const bf16x8*)&lds[0][1][aB + j*512];
    #pragma unroll
    for(int i=0;i<4;i++) fa0[i] = *(const bf16x8*)&lds[0][0][aA + i*512];

    #define BODY(T, FA_C, FB_C, FA_N, FB_N) { \
        const int t_ = (T); \
        if (t_+2 < NT)      asm volatile("s_waitcnt vmcnt(2)\ns_barrier" ::: "memory"); \
        else if (t_+1 < NT) asm volatile("s_waitcnt vmcnt(0)\ns_barrier" ::: "memory"); \
        if (t_+1 < NT){ \
            const ushort_t* pA = lds[(t_+1)&3][0]; \
            const ushort_t* pB = lds[(t_+1)&3][1]; \
            _Pragma("unroll") \
            for(int j=0;j<4;j++) FB_N[j] = *(const bf16x8*)&pB[aB + j*512]; \
            _Pragma("unroll") \
            for(int i=0;i<4;i++) FA_N[i] = *(const bf16x8*)&pA[aA + i*512]; \
        } \
        if (t_+3 < NT){ \
            const int kc = koff + (t_+3)*32; \
            GLD_LDS16(aS + kc, &lds[(t_+3)&3][0][sdst]); \
            GLD_LDS16(wS + kc, &lds[(t_+3)&3][1][sdst]); \
        } \
        __builtin_amdgcn_sched_barrier(0); \
        __builtin_amdgcn_s_setprio(1); \
        _Pragma("unroll") \
        for(int i=0;i<4;i++){ \
            _Pragma("unroll") \
            for(int j=0;j<4;j++) \
                acc[i][j] = __builtin_amdgcn_mfma_f32_16x16x32_bf16(FA_C[i], FB_C[j], acc[i][j],0,0,0); \
        } \
        __builtin_amdgcn_s_setprio(0); \
    }

    for(int t=0; t<NT; t+=2){
        BODY(t,   fa0, fb0, fa1, fb1);
        BODY(t+1, fa1, fb1, fa0, fb0);
    }
    #undef BODY

    void* dst = Cptr;
    int cb = col0;
    if (SPLIT && col0 >= ldc){ dst = C2; cb = col0 - ldc; }
    const int rbase = row0 + wr*64 + lq*4;
    const int cbase = cb + wc*64 + lr;
    #pragma unroll
    for(int i=0;i<4;i++){
        #pragma unroll
        for(int r=0;r<4;r++){
            const int row = rbase + i*16 + r;
            #pragma unroll
            for(int j=0;j<4;j++){
                const int col = cbase + j*16;
                const float v = acc[i][j][r];
                if (OUTBF) ((ushort_t*)dst)[(size_t)row*ldc + col] = f2bf(v);
                else       ((float*)dst)[(size_t)row*ldc + col] = v;
            }
        }
    }
}

// two f32 -> bf16 casts in one launch (hs + w_in), 4 elems/thread
__global__ __launch_bounds__(256)
void cvt2_bf16(const float* __restrict__ in1, ushort_t* __restrict__ out1, int n1_4,
               const float* __restrict__ in2, ushort_t* __restrict__ out2, int n2_4)
{
    const int i = blockIdx.x*256 + threadIdx.x;
    const float* in; ushort_t* out; int j;
    if (i < n1_4){ in = in1; out = out1; j = i; }
    else if (i < n1_4 + n2_4){ in = in2; out = out2; j = i - n1_4; }
    else return;
    float4 v = *(const float4*)(in + (size_t)j*4);
    union { ushort_t u[4]; uint2 q; } p;
    p.u[0]=f2bf(v.x); p.u[1]=f2bf(v.y); p.u[2]=f2bf(v.z); p.u[3]=f2bf(v.w);
    *(uint2*)(out + (size_t)j*4) = p.q;
}

// w_xproj 160x4096 f32 -> 256x4096 bf16 (rows 160..255 zero) + w_dt cvt
__global__ __launch_bounds__(256)
void cvt_xw(const float* __restrict__ wx, ushort_t* __restrict__ wx_bf,
            const float* __restrict__ wdt, ushort_t* __restrict__ wdt_bf)
{
    const int i = blockIdx.x*256 + threadIdx.x;
    union { ushort_t u[4]; uint2 q; } p;
    if (i < 262144){                        // 256*4096/4
        const int row = i >> 10;
        const int c4  = i & 1023;
        if (row < 160){
            float4 v = *(const float4*)(wx + (size_t)row*4096 + c4*4);
            p.u[0]=f2bf(v.x); p.u[1]=f2bf(v.y); p.u[2]=f2bf(v.z); p.u[3]=f2bf(v.w);
        } else { p.u[0]=0; p.u[1]=0; p.u[2]=0; p.u[3]=0; }
        *(uint2*)(wx_bf + (size_t)i*4) = p.q;
    } else {
        const int j = i - 262144;           // DINNER*DTRANK/4 = 131072
        float4 v = *(const float4*)(wdt + (size_t)j*4);
        p.u[0]=f2bf(v.x); p.u[1]=f2bf(v.y); p.u[2]=f2bf(v.z); p.u[3]=f2bf(v.w);
        *(uint2*)(wdt_bf + (size_t)j*4) = p.q;
    }
}

// reduce split-K partials P[8][4096][256] -> xdbl f32 (ld 160) + dtlo bf16 (ld 128)
__global__ __launch_bounds__(256)
void reduce_xproj(const float* __restrict__ P, float* __restrict__ xdbl,
                  ushort_t* __restrict__ dtlo)
{
    const int row = blockIdx.x;
    const int col = threadIdx.x;
    float s = 0.f;
    #pragma unroll
    for(int z=0; z<8; z++)
        s += P[(size_t)z*MROWS*256 + (size_t)row*256 + col];
    if (col < 160) xdbl[(size_t)row*160 + col] = s;
    if (col < DTRANK) dtlo[(size_t)row*DTRANK + col] = f2bf(s);
}

// depthwise causal conv (k=4) + bias + silu, bf16 in/out
__global__ __launch_bounds__(256)
void conv_silu_bf(const ushort_t* __restrict__ xb, const float* __restrict__ w,
                  const float* __restrict__ bias, ushort_t* __restrict__ xc)
{
    const int gid = blockIdx.x*256 + threadIdx.x;
    const int d = gid & (DINNER-1);
    const int t = gid >> 12;
    const int l = t & (L_-1);
    float s = bias[d];
    #pragma unroll
    for(int j=0;j<DCONV;j++){
        const int ll = l - (DCONV-1) + j;
        if (ll >= 0)
            s = fmaf(bf2f(xb[(size_t)(t-(DCONV-1)+j)*DINNER + d]), w[d*DCONV+j], s);
    }
    xc[(size_t)t*DINNER + d] = f2bf(s * sigmoidf_(s));
}

// ---- chunked scan, one thread per channel d, 16 states in registers ----
__global__ __launch_bounds__(256)
void scan_phase1(const ushort_t* __restrict__ dt_bf,
                 const ushort_t* __restrict__ xconv,
                 const float* __restrict__ xdbl,
                 const float* __restrict__ A_log,
                 float* __restrict__ sc_h, float* __restrict__ sc_S)
{
    const int tid = threadIdx.x;
    const int d = blockIdx.x*256 + tid;
    const int chunk = blockIdx.y;
    const int b = blockIdx.z;
    const int l0 = chunk*CLEN;

    __shared__ float Bs[CLEN][DSTATE];
    for(int i=tid; i<CLEN*DSTATE; i+=256){
        const int row = i >> 4, n = i & 15;
        Bs[row][n] = xdbl[(size_t)(b*L_ + l0 + row)*160 + DTRANK + n];
    }
    float negA[DSTATE];
    #pragma unroll
    for(int n=0;n<DSTATE;n++) negA[n] = -expf(A_log[d*DSTATE + n]) * LOG2E;
    __syncthreads();

    float h[DSTATE], S[DSTATE];
    #pragma unroll
    for(int n=0;n<DSTATE;n++){ h[n]=0.f; S[n]=0.f; }

    size_t idx = (size_t)(b*L_ + l0)*DINNER + d;
    float dt_c = bf2f(dt_bf[idx]);
    float xv_c = bf2f(xconv[idx]);
    for(int l=0;l<CLEN;l++){
        float dt_n = 0.f, xv_n = 0.f;
        if (l+1 < CLEN){
            dt_n = bf2f(dt_bf[idx + DINNER]);
            xv_n = bf2f(xconv[idx + DINNER]);
        }
        const float dx = dt_c * xv_c;
        #pragma unroll
        for(int n=0;n<DSTATE;n++){
            const float t = dt_c * negA[n];
            S[n] += t;
            h[n] = fmaf(h[n], fast_exp2(t), dx*Bs[l][n]);
        }
        dt_c = dt_n; xv_c = xv_n;
        idx += DINNER;
    }
    const size_t o = (size_t)(b*NCHUNK + chunk)*DSTATE*DINNER + d;
    #pragma unroll
    for(int n=0;n<DSTATE;n++){
        sc_h[o + (size_t)n*DINNER] = h[n];
        sc_S[o + (size_t)n*DINNER] = S[n];
    }
}

// scan phase2 (blocks >= CVW) fused with w_out f32->bf16 cvt (blocks < CVW)
#define CVW 8192   // DMODEL*DINNER/4/256
__global__ __launch_bounds__(256)
void scan_phase2_cvt(float* __restrict__ sc_h, const float* __restrict__ sc_S,
                     const float* __restrict__ w_out, ushort_t* __restrict__ wo_bf)
{
    if (blockIdx.x < CVW){
        const int i = blockIdx.x*256 + threadIdx.x;
        float4 v = *(const float4*)(w_out + (size_t)i*4);
        union { ushort_t u[4]; uint2 q; } p;
        p.u[0]=f2bf(v.x); p.u[1]=f2bf(v.y); p.u[2]=f2bf(v.z); p.u[3]=f2bf(v.w);
        *(uint2*)(wo_bf + (size_t)i*4) = p.q;
        return;
    }
    const int gid = (blockIdx.x - CVW)*256 + threadIdx.x;
    const int b = gid / (DSTATE*DINNER);
    const int rem = gid - b*DSTATE*DINNER;
    const size_t base = (size_t)b*NCHUNK*DSTATE*DINNER + rem;
    float H = 0.f;
    #pragma unroll
    for(int c=0;c<NCHUNK;c++){
        const size_t idx = base + (size_t)c*DSTATE*DINNER;
        const float he = sc_h[idx];
        const float S  = sc_S[idx];
        sc_h[idx] = H;
        H = fmaf(fast_exp2(S), H, he);
    }
}

// phase3: y written IN-PLACE over dt_bf (y[l] stored after dt[l+1] lookahead
// read; threads own disjoint d columns) -> no __restrict__ on dt/y.
__global__ __launch_bounds__(256)
void scan_phase3(const ushort_t* dt_bf,
                 const ushort_t* __restrict__ xconv,
                 const float* __restrict__ xdbl,
                 const ushort_t* __restrict__ z_bf,
                 const float* __restrict__ A_log,
                 const float* __restrict__ Dvec,
                 const float* __restrict__ sc_h,
                 ushort_t* y_bf)
{
    const int tid = threadIdx.x;
    const int d = blockIdx.x*256 + tid;
    const int chunk = blockIdx.y;
    const int b = blockIdx.z;
    const int l0 = chunk*CLEN;

    __shared__ float BCs[CLEN][2*DSTATE];
    for(int i=tid; i<CLEN*2*DSTATE; i+=256){
        const int row = i >> 5, c = i & 31;
        BCs[row][c] = xdbl[(size_t)(b*L_ + l0 + row)*160 + DTRANK + c];
    }
    float negA[DSTATE];
    #pragma unroll
    for(int n=0;n<DSTATE;n++) negA[n] = -expf(A_log[d*DSTATE + n]) * LOG2E;
    const float Dv = Dvec[d];
    float h[DSTATE];
    const size_t o = (size_t)(b*NCHUNK + chunk)*DSTATE*DINNER + d;
    #pragma unroll
    for(int n=0;n<DSTATE;n++) h[n] = sc_h[o + (size_t)n*DINNER];
    __syncthreads();

    size_t idx = (size_t)(b*L_ + l0)*DINNER + d;
    float dt_c = bf2f(dt_bf[idx]);
    float xv_c = bf2f(xconv[idx]);
    float zv_c = bf2f(z_bf[idx]);
    for(int l=0;l<CLEN;l++){
        float dt_n = 0.f, xv_n = 0.f, zv_n = 0.f;
        if (l+1 < CLEN){
            dt_n = bf2f(dt_bf[idx + DINNER]);
            xv_n = bf2f(xconv[idx + DINNER]);
            zv_n = bf2f(z_bf[idx + DINNER]);
        }
        const float dx = dt_c * xv_c;
        float y = 0.f;
        #pragma unroll
        for(int n=0;n<DSTATE;n++){
            const float t = dt_c * negA[n];
            h[n] = fmaf(h[n], fast_exp2(t), dx*BCs[l][n]);
            y = fmaf(h[n], BCs[l][DSTATE+n], y);
        }
        const float g = zv_c * sigmoidf_(zv_c);
        y_bf[idx] = f2bf(fmaf(xv_c, Dv, y) * g);
        dt_c = dt_n; xv_c = xv_n; zv_c = zv_n;
        idx += DINNER;
    }
}

extern "C" void kernel_launch(void* const* d_in, const int* in_sizes, int n_in,
                              void* d_out, int out_size, void* d_ws, size_t ws_size,
                              hipStream_t stream) {
    const float* hs      = (const float*)d_in[0];
    const float* w_in    = (const float*)d_in[1];
    const float* w_conv  = (const float*)d_in[2];
    const float* b_conv  = (const float*)d_in[3];
    const float* w_xproj = (const float*)d_in[4];
    const float* w_dt    = (const float*)d_in[5];
    const float* b_dt    = (const float*)d_in[6];
    const float* w_out   = (const float*)d_in[7];
    const float* A_log   = (const float*)d_in[8];
    const float* Dvec    = (const float*)d_in[9];
    float* out = (float*)d_out;

    // workspace layout (peak 176 MiB):
    // [0,32M)    x_bf -> after conv: xdbl@0, wx_bf@4M, dtlo@6M, wdt@7M, sc_h@8M(16.75M)
    // [32M,64M)  z_bf               (live to phase3)
    // [64M,96M)  xconv              (live to phase3)
    // [96M,128M) wi_bf -> dt_bf (dt_proj) -> y_bf IN-PLACE (phase3) -> out_proj A
    // [128M,144M) hs_bf -> sc_S (phase1..phase2)
    // [144M,176M) xp_par (x_proj partials, dead after reduce) -> wo_bf@144M (16M)
    char* base = (char*)d_ws;
    ushort_t* x_bf   = (ushort_t*)(base);
    float*    xdbl   = (float*)   (base);
    ushort_t* wx_bf  = (ushort_t*)(base + (4u<<20));
    ushort_t* dtlo_bf= (ushort_t*)(base + (6u<<20));
    ushort_t* wdt_bf = (ushort_t*)(base + (7u<<20));
    float*    sc_h   = (float*)   (base + (8u<<20));
    ushort_t* z_bf   = (ushort_t*)(base + (32u<<20));
    ushort_t* xconv  = (ushort_t*)(base + (64u<<20));
    ushort_t* wi_bf  = (ushort_t*)(base + (96u<<20));
    ushort_t* dt_bf  = (ushort_t*)(base + (96u<<20));
    ushort_t* y_bf   = (ushort_t*)(base + (96u<<20));   // in-place over dt_bf
    ushort_t* hs_bf  = (ushort_t*)(base + (128u<<20));
    float*    sc_S   = (float*)   (base + (128u<<20));
    float*    xp_par = (float*)   (base + (144u<<20));  // 8*4096*256*4 = 32 MiB
    ushort_t* wo_bf  = (ushort_t*)(base + (144u<<20));  // 16 MiB, after reduce

    dim3 blk(256);
    dim3 blkW(1024);

    // convert activations + in_proj weights to bf16 (one launch)
    cvt2_bf16<<<dim3((MROWS*DMODEL/4 + 2*DINNER*DMODEL/4)/256), blk, 0, stream>>>(
        hs, hs_bf, MROWS*DMODEL/4, w_in, wi_bf, 2*DINNER*DMODEL/4);

    // fused in_proj (256^2 v6 pipelined): N=8192, split x / z halves
    gemm_256w<1,1><<<dim3(MROWS/256, 2*DINNER/256), blkW, 0, stream>>>(
        hs_bf, DMODEL, wi_bf, DMODEL, x_bf, z_bf, DINNER, DMODEL);

    // conv + silu -> xconv bf16 (x_bf region becomes free after this)
    conv_silu_bf<<<dim3((size_t)MROWS*DINNER/256), blk, 0, stream>>>(x_bf, w_conv, b_conv, xconv);

    // w_xproj pad-cvt + w_dt cvt (one launch; [0,32M) region free now)
    cvt_xw<<<dim3((262144 + 131072)/256), blk, 0, stream>>>(w_xproj, wx_bf, w_dt, wdt_bf);

    // x_proj: split-K x 8 into f32 partials, then reduce (+fused dtlo cvt)
    gemm_mfma<0,0,0,1><<<dim3(MROWS/128, 2, 8), blk, 0, stream>>>(
        xconv, DINNER, wx_bf, DINNER, xp_par, nullptr, 256, DINNER/8, nullptr);
    reduce_xproj<<<dim3(MROWS), blk, 0, stream>>>(xp_par, xdbl, dtlo_bf);

    // dt_proj + bias + softplus -> dt_bf
    gemm_mfma<1,1,0,0><<<dim3(MROWS/128, DINNER/128), blk, 0, stream>>>(
        dtlo_bf, DTRANK, wdt_bf, DTRANK, dt_bf, nullptr, DINNER, DTRANK, b_dt);

    // chunked selective scan (thread-per-channel, coalesced)
    dim3 sgrid(DINNER/256, NCHUNK, B_);
    scan_phase1<<<sgrid, blk, 0, stream>>>(dt_bf, xconv, xdbl, A_log, sc_h, sc_S);

    // phase2 + w_out cvt in one launch (wo_bf region dead since reduce_xproj)
    scan_phase2_cvt<<<dim3(CVW + B_*DSTATE*DINNER/256), blk, 0, stream>>>(
        sc_h, sc_S, w_out, wo_bf);

    // phase3: y overwrites dt_bf in place
    scan_phase3<<<sgrid, blk, 0, stream>>>(dt_bf, xconv, xdbl, z_bf, A_log, Dvec, sc_h, y_bf);

    // out_proj (128^2 kernel, 512 blocks -> full machine, direct f32 out)
    gemm_mfma<0,0,0,0><<<dim3(MROWS/128, DMODEL/128), blk, 0, stream>>>(
        y_bf, DINNER, wo_bf, DINNER, out, nullptr, DMODEL, DINNER, nullptr);
}

// Round 7
// 669.914 us; speedup vs baseline: 1.2620x; 1.2620x over previous
//
#include <hip/hip_runtime.h>
#include <math.h>

#define B_ 2
#define L_ 2048
#define DMODEL 2048
#define DINNER 4096
#define DSTATE 16
#define DCONV 4
#define DTRANK 128
#define NCHUNK 32
#define CLEN 64           // L_/NCHUNK
#define MROWS 4096        // B_*L_

typedef unsigned short ushort_t;
typedef unsigned int uint_t;
typedef __attribute__((ext_vector_type(8))) short bf16x8;
typedef __attribute__((ext_vector_type(4))) float floatx4;

__device__ __forceinline__ float sigmoidf_(float x){ return 1.f/(1.f+__expf(-x)); }
__device__ __forceinline__ ushort_t f2bf(float f){
    uint_t u = __builtin_bit_cast(uint_t, f);
    return (ushort_t)((u + 0x7FFFu + ((u >> 16) & 1u)) >> 16);
}
__device__ __forceinline__ float bf2f(ushort_t h){
    return __builtin_bit_cast(float, (uint_t)h << 16);
}
__device__ __forceinline__ float fast_exp2(float x){
#if __has_builtin(__builtin_amdgcn_exp2f)
    return __builtin_amdgcn_exp2f(x);
#else
    return exp2f(x);
#endif
}
#define LOG2E 1.44269504088896f

#define GLD_LDS16(g, l) __builtin_amdgcn_global_load_lds( \
    (const __attribute__((address_space(1))) void*)(g),   \
    (__attribute__((address_space(3))) void*)(l), 16, 0, 0)

// ---------------------------------------------------------------------------
// 128x128 bf16 MFMA GEMM (m97 structure) — used for x_proj (split-K, N=256),
// dt_proj (K=128), out_proj (N=2048 -> 512 blocks fill the machine).
// ---------------------------------------------------------------------------
template<int OUTBF, int EPI, int SPLIT, int KSPLIT>
__global__ __launch_bounds__(256)
void gemm_mfma(const ushort_t* __restrict__ Aptr, int lda,
               const ushort_t* __restrict__ W, int ldw,
               void* __restrict__ Cptr, void* __restrict__ C2,
               int ldc, int Klen,
               const float* __restrict__ bias)
{
    __shared__ ushort_t lsA[128*64];
    __shared__ ushort_t lsW[128*64];
    const int tid  = threadIdx.x;
    const int row0 = blockIdx.x * 128;
    const int col0 = blockIdx.y * 128;
    const int koff = KSPLIT ? blockIdx.z * Klen : 0;
    const int lane = tid & 63;
    const int wv   = tid >> 6;
    const int wm   = (wv >> 1) * 64;
    const int wn   = (wv & 1) * 64;
    const int lr   = lane & 15;
    const int lq   = lane >> 4;

    floatx4 acc[4][4];
    #pragma unroll
    for(int i=0;i<4;i++)
        #pragma unroll
        for(int j=0;j<4;j++)
            #pragma unroll
            for(int r=0;r<4;r++) acc[i][j][r] = 0.f;

    for(int k0 = koff; k0 < koff + Klen; k0 += 64){
        #pragma unroll
        for(int it=0; it<4; it++){
            const int slot = it*256 + tid;
            const int row  = slot >> 3;
            const int p    = slot & 7;
            const int s    = p ^ (row & 7);
            const ushort_t* gw = W    + (size_t)(col0 + row)*ldw + k0 + s*8;
            const ushort_t* ga = Aptr + (size_t)(row0 + row)*lda + k0 + s*8;
            GLD_LDS16(gw, &lsW[slot*8]);
            GLD_LDS16(ga, &lsA[slot*8]);
        }
        __syncthreads();

        #pragma unroll
        for(int kk=0; kk<2; kk++){
            bf16x8 af[4], bw[4];
            #pragma unroll
            for(int i=0;i<4;i++){
                const int ra = wm + i*16 + lr;
                const int rb = wn + i*16 + lr;
                af[i] = *(const bf16x8*)&lsA[ra*64 + (((kk*4+lq) ^ (ra&7))*8)];
                bw[i] = *(const bf16x8*)&lsW[rb*64 + (((kk*4+lq) ^ (rb&7))*8)];
            }
            #pragma unroll
            for(int i=0;i<4;i++)
                #pragma unroll
                for(int j=0;j<4;j++)
                    acc[i][j] = __builtin_amdgcn_mfma_f32_16x16x32_bf16(af[i], bw[j], acc[i][j], 0, 0, 0);
        }
        __syncthreads();
    }

    void* dst = Cptr;
    int cbase = col0;
    if (SPLIT && col0 >= ldc){ dst = C2; cbase = col0 - ldc; }
    const size_t zoff = KSPLIT ? (size_t)blockIdx.z * MROWS * ldc : 0;

    #pragma unroll
    for(int i=0;i<4;i++){
        #pragma unroll
        for(int r=0;r<4;r++){
            const int row = row0 + wm + i*16 + lq*4 + r;
            #pragma unroll
            for(int j=0;j<4;j++){
                const int col = cbase + wn + j*16 + lr;
                float v = acc[i][j][r];
                if (EPI){
                    v += bias[col];
                    v = (v > 20.f) ? v : log1pf(expf(v));
                }
                if (OUTBF) ((ushort_t*)dst)[(size_t)row*ldc + col] = f2bf(v);
                else       ((float*)  dst)[zoff + (size_t)row*ldc + col] = v;
            }
        }
    }
}

// ---------------------------------------------------------------------------
// 256x256 bf16 GEMM v7: C[M,N]=A[M,K]*W[N,K]^T.
// 1024 thr = 16 waves (4M x 4N), per-wave 64x64, BK=32, 4 waves/SIMD.
// Register shape = v5 EXACTLY (64 AGPR acc + single frag set, ~120 total,
// fits the 128/wave cap at 4 waves/SIMD — v6's 2nd frag set spilled:
// WRITE_SIZE 65MB -> 657MB scratch traffic).
// v7 schedule — reads AFTER MFMA (loop-carried, same registers):
//   body t:
//     vmcnt(2); s_barrier;          // tile t+1 landed (staged @ body t-2)
//     STG tile t+3 -> buf (t+3)&3;  // == buf (t-1)&3, WAR-safe: its readers
//                                   //    drained before MFMA(t-1) < barrier
//     setprio(1); 16 MFMA on frags(t); setprio(0);
//     sched_barrier(0);             // pin reads below MFMAs (no renaming)
//     8 ds_read frags(t+1) from buf (t+1)&3  -> same af/bw regs
//   If MFMA acceptance is queued, each wave issues reads(t+1) early and the
//   LDS port drains 128KB/tile UNDER the 1242-cyc/SIMD MFMA grind -> wall
//   ~1500 cyc/tile (vs 2340 serialized). If acceptance blocks in-order,
//   this is neutral — a clean discriminator at zero spill risk.
// vmcnt ladder: at body top outstanding = stage(t+1)[2] + stage(t+2)[2] = 4
//   -> vmcnt(2) waits stage(t+1). Tail: vmcnt(0) when t+2==NT; last body
//   has no wait/barrier (no staging, no reads).
// Swizzle (0 conflicts measured): chunk c of row r at slot c ^ ((r>>1)&3);
// linear gload_lds dest, pre-swizzled per-lane source.
// ---------------------------------------------------------------------------
template<int OUTBF, int SPLIT>
__global__ __launch_bounds__(1024, 4)
void gemm_256w(const ushort_t* __restrict__ Aptr, int lda,
               const ushort_t* __restrict__ W, int ldw,
               void* __restrict__ Cptr, void* __restrict__ C2,
               int ldc, int Klen)
{
    __shared__ ushort_t lds[4][2][8192];   // [buf][A/W][256 rows x 32]
    const int tid  = threadIdx.x;
    const int row0 = blockIdx.x * 256;
    const int col0 = blockIdx.y * 256;
    const int NT   = Klen >> 5;            // K-tile = 32
    const int lane = tid & 63;
    const int wv   = tid >> 6;             // 0..15
    const int wr   = wv >> 2;              // 0..3 : M quarter (64 rows)
    const int wc   = wv & 3;               // 0..3 : N quarter (64 cols)
    const int lr   = lane & 15;
    const int lq   = lane >> 4;            // 0..3 : 16B chunk within row

    // staging: thread tid covers (row = tid>>2, slot p = tid&3);
    // source chunk c = p ^ ((row>>1)&3); dest linear tid*16B.
    const int srow = tid >> 2;
    const int sc   = (tid & 3) ^ ((srow >> 1) & 3);
    const ushort_t* aS = Aptr + (size_t)(row0 + srow)*lda + sc*8;
    const ushort_t* wS = W    + (size_t)(col0 + srow)*ldw + sc*8;
    const int sdst = tid*8;

    // ds_read bases (ushort units): frag i at base + i*512 (16 rows x 32)
    const int rA = wr*64 + lr;
    const int rB = wc*64 + lr;
    const int aA = rA*32 + ((lq ^ ((rA>>1)&3))*8);
    const int aB = rB*32 + ((lq ^ ((rB>>1)&3))*8);

    floatx4 acc[4][4];
    #pragma unroll
    for(int i=0;i<4;i++)
        #pragma unroll
        for(int j=0;j<4;j++)
            #pragma unroll
            for(int r=0;r<4;r++) acc[i][j][r] = 0.f;

    bf16x8 af[4], bw[4];

    // prologue: stage tiles 0,1,2; wait tile 0; read frags(0)
    GLD_LDS16(aS,      &lds[0][0][sdst]);
    GLD_LDS16(wS,      &lds[0][1][sdst]);
    GLD_LDS16(aS + 32, &lds[1][0][sdst]);
    GLD_LDS16(wS + 32, &lds[1][1][sdst]);
    GLD_LDS16(aS + 64, &lds[2][0][sdst]);
    GLD_LDS16(wS + 64, &lds[2][1][sdst]);
    asm volatile("s_waitcnt vmcnt(4)\ns_barrier" ::: "memory");
    #pragma unroll
    for(int j=0;j<4;j++) bw[j] = *(const bf16x8*)&lds[0][1][aB + j*512];
    #pragma unroll
    for(int i=0;i<4;i++) af[i] = *(const bf16x8*)&lds[0][0][aA + i*512];

    for(int t=0; t<NT; ++t){
        if (t+2 < NT)      asm volatile("s_waitcnt vmcnt(2)\ns_barrier" ::: "memory");
        else if (t+1 < NT) asm volatile("s_waitcnt vmcnt(0)\ns_barrier" ::: "memory");
        if (t+3 < NT){
            const int kc = (t+3)*32;
            GLD_LDS16(aS + kc, &lds[(t+3)&3][0][sdst]);
            GLD_LDS16(wS + kc, &lds[(t+3)&3][1][sdst]);
        }
        __builtin_amdgcn_s_setprio(1);
        #pragma unroll
        for(int i=0;i<4;i++)
            #pragma unroll
            for(int j=0;j<4;j++)
                acc[i][j] = __builtin_amdgcn_mfma_f32_16x16x32_bf16(af[i], bw[j], acc[i][j],0,0,0);
        __builtin_amdgcn_s_setprio(0);
        __builtin_amdgcn_sched_barrier(0);
        if (t+1 < NT){
            const ushort_t* pA = lds[(t+1)&3][0];
            const ushort_t* pB = lds[(t+1)&3][1];
            #pragma unroll
            for(int j=0;j<4;j++) bw[j] = *(const bf16x8*)&pB[aB + j*512];
            #pragma unroll
            for(int i=0;i<4;i++) af[i] = *(const bf16x8*)&pA[aA + i*512];
        }
    }

    void* dst = Cptr;
    int cb = col0;
    if (SPLIT && col0 >= ldc){ dst = C2; cb = col0 - ldc; }
    const int rbase = row0 + wr*64 + lq*4;
    const int cbase = cb + wc*64 + lr;
    #pragma unroll
    for(int i=0;i<4;i++){
        #pragma unroll
        for(int r=0;r<4;r++){
            const int row = rbase + i*16 + r;
            #pragma unroll
            for(int j=0;j<4;j++){
                const int col = cbase + j*16;
                const float v = acc[i][j][r];
                if (OUTBF) ((ushort_t*)dst)[(size_t)row*ldc + col] = f2bf(v);
                else       ((float*)dst)[(size_t)row*ldc + col] = v;
            }
        }
    }
}

// two f32 -> bf16 casts in one launch (hs + w_in), 4 elems/thread
__global__ __launch_bounds__(256)
void cvt2_bf16(const float* __restrict__ in1, ushort_t* __restrict__ out1, int n1_4,
               const float* __restrict__ in2, ushort_t* __restrict__ out2, int n2_4)
{
    const int i = blockIdx.x*256 + threadIdx.x;
    const float* in; ushort_t* out; int j;
    if (i < n1_4){ in = in1; out = out1; j = i; }
    else if (i < n1_4 + n2_4){ in = in2; out = out2; j = i - n1_4; }
    else return;
    float4 v = *(const float4*)(in + (size_t)j*4);
    union { ushort_t u[4]; uint2 q; } p;
    p.u[0]=f2bf(v.x); p.u[1]=f2bf(v.y); p.u[2]=f2bf(v.z); p.u[3]=f2bf(v.w);
    *(uint2*)(out + (size_t)j*4) = p.q;
}

// w_xproj 160x4096 f32 -> 256x4096 bf16 (rows 160..255 zero) + w_dt cvt
__global__ __launch_bounds__(256)
void cvt_xw(const float* __restrict__ wx, ushort_t* __restrict__ wx_bf,
            const float* __restrict__ wdt, ushort_t* __restrict__ wdt_bf)
{
    const int i = blockIdx.x*256 + threadIdx.x;
    union { ushort_t u[4]; uint2 q; } p;
    if (i < 262144){                        // 256*4096/4
        const int row = i >> 10;
        const int c4  = i & 1023;
        if (row < 160){
            float4 v = *(const float4*)(wx + (size_t)row*4096 + c4*4);
            p.u[0]=f2bf(v.x); p.u[1]=f2bf(v.y); p.u[2]=f2bf(v.z); p.u[3]=f2bf(v.w);
        } else { p.u[0]=0; p.u[1]=0; p.u[2]=0; p.u[3]=0; }
        *(uint2*)(wx_bf + (size_t)i*4) = p.q;
    } else {
        const int j = i - 262144;           // DINNER*DTRANK/4 = 131072
        float4 v = *(const float4*)(wdt + (size_t)j*4);
        p.u[0]=f2bf(v.x); p.u[1]=f2bf(v.y); p.u[2]=f2bf(v.z); p.u[3]=f2bf(v.w);
        *(uint2*)(wdt_bf + (size_t)j*4) = p.q;
    }
}

// reduce split-K partials P[8][4096][256] -> xdbl f32 (ld 160) + dtlo bf16 (ld 128)
__global__ __launch_bounds__(256)
void reduce_xproj(const float* __restrict__ P, float* __restrict__ xdbl,
                  ushort_t* __restrict__ dtlo)
{
    const int row = blockIdx.x;
    const int col = threadIdx.x;
    float s = 0.f;
    #pragma unroll
    for(int z=0; z<8; z++)
        s += P[(size_t)z*MROWS*256 + (size_t)row*256 + col];
    if (col < 160) xdbl[(size_t)row*160 + col] = s;
    if (col < DTRANK) dtlo[(size_t)row*DTRANK + col] = f2bf(s);
}

// depthwise causal conv (k=4) + bias + silu, bf16 in/out
__global__ __launch_bounds__(256)
void conv_silu_bf(const ushort_t* __restrict__ xb, const float* __restrict__ w,
                  const float* __restrict__ bias, ushort_t* __restrict__ xc)
{
    const int gid = blockIdx.x*256 + threadIdx.x;
    const int d = gid & (DINNER-1);
    const int t = gid >> 12;
    const int l = t & (L_-1);
    float s = bias[d];
    #pragma unroll
    for(int j=0;j<DCONV;j++){
        const int ll = l - (DCONV-1) + j;
        if (ll >= 0)
            s = fmaf(bf2f(xb[(size_t)(t-(DCONV-1)+j)*DINNER + d]), w[d*DCONV+j], s);
    }
    xc[(size_t)t*DINNER + d] = f2bf(s * sigmoidf_(s));
}

// ---- chunked scan, one thread per channel d, 16 states in registers ----
__global__ __launch_bounds__(256)
void scan_phase1(const ushort_t* __restrict__ dt_bf,
                 const ushort_t* __restrict__ xconv,
                 const float* __restrict__ xdbl,
                 const float* __restrict__ A_log,
                 float* __restrict__ sc_h, float* __restrict__ sc_S)
{
    const int tid = threadIdx.x;
    const int d = blockIdx.x*256 + tid;
    const int chunk = blockIdx.y;
    const int b = blockIdx.z;
    const int l0 = chunk*CLEN;

    __shared__ float Bs[CLEN][DSTATE];
    for(int i=tid; i<CLEN*DSTATE; i+=256){
        const int row = i >> 4, n = i & 15;
        Bs[row][n] = xdbl[(size_t)(b*L_ + l0 + row)*160 + DTRANK + n];
    }
    float negA[DSTATE];
    #pragma unroll
    for(int n=0;n<DSTATE;n++) negA[n] = -expf(A_log[d*DSTATE + n]) * LOG2E;
    __syncthreads();

    float h[DSTATE], S[DSTATE];
    #pragma unroll
    for(int n=0;n<DSTATE;n++){ h[n]=0.f; S[n]=0.f; }

    size_t idx = (size_t)(b*L_ + l0)*DINNER + d;
    float dt_c = bf2f(dt_bf[idx]);
    float xv_c = bf2f(xconv[idx]);
    for(int l=0;l<CLEN;l++){
        float dt_n = 0.f, xv_n = 0.f;
        if (l+1 < CLEN){
            dt_n = bf2f(dt_bf[idx + DINNER]);
            xv_n = bf2f(xconv[idx + DINNER]);
        }
        const float dx = dt_c * xv_c;
        #pragma unroll
        for(int n=0;n<DSTATE;n++){
            const float t = dt_c * negA[n];
            S[n] += t;
            h[n] = fmaf(h[n], fast_exp2(t), dx*Bs[l][n]);
        }
        dt_c = dt_n; xv_c = xv_n;
        idx += DINNER;
    }
    const size_t o = (size_t)(b*NCHUNK + chunk)*DSTATE*DINNER + d;
    #pragma unroll
    for(int n=0;n<DSTATE;n++){
        sc_h[o + (size_t)n*DINNER] = h[n];
        sc_S[o + (size_t)n*DINNER] = S[n];
    }
}

// scan phase2 (blocks >= CVW) fused with w_out f32->bf16 cvt (blocks < CVW)
#define CVW 8192   // DMODEL*DINNER/4/256
__global__ __launch_bounds__(256)
void scan_phase2_cvt(float* __restrict__ sc_h, const float* __restrict__ sc_S,
                     const float* __restrict__ w_out, ushort_t* __restrict__ wo_bf)
{
    if (blockIdx.x < CVW){
        const int i = blockIdx.x*256 + threadIdx.x;
        float4 v = *(const float4*)(w_out + (size_t)i*4);
        union { ushort_t u[4]; uint2 q; } p;
        p.u[0]=f2bf(v.x); p.u[1]=f2bf(v.y); p.u[2]=f2bf(v.z); p.u[3]=f2bf(v.w);
        *(uint2*)(wo_bf + (size_t)i*4) = p.q;
        return;
    }
    const int gid = (blockIdx.x - CVW)*256 + threadIdx.x;
    const int b = gid / (DSTATE*DINNER);
    const int rem = gid - b*DSTATE*DINNER;
    const size_t base = (size_t)b*NCHUNK*DSTATE*DINNER + rem;
    float H = 0.f;
    #pragma unroll
    for(int c=0;c<NCHUNK;c++){
        const size_t idx = base + (size_t)c*DSTATE*DINNER;
        const float he = sc_h[idx];
        const float S  = sc_S[idx];
        sc_h[idx] = H;
        H = fmaf(fast_exp2(S), H, he);
    }
}

// phase3: y written IN-PLACE over dt_bf (y[l] stored after dt[l+1] lookahead
// read; threads own disjoint d columns) -> no __restrict__ on dt/y.
__global__ __launch_bounds__(256)
void scan_phase3(const ushort_t* dt_bf,
                 const ushort_t* __restrict__ xconv,
                 const float* __restrict__ xdbl,
                 const ushort_t* __restrict__ z_bf,
                 const float* __restrict__ A_log,
                 const float* __restrict__ Dvec,
                 const float* __restrict__ sc_h,
                 ushort_t* y_bf)
{
    const int tid = threadIdx.x;
    const int d = blockIdx.x*256 + tid;
    const int chunk = blockIdx.y;
    const int b = blockIdx.z;
    const int l0 = chunk*CLEN;

    __shared__ float BCs[CLEN][2*DSTATE];
    for(int i=tid; i<CLEN*2*DSTATE; i+=256){
        const int row = i >> 5, c = i & 31;
        BCs[row][c] = xdbl[(size_t)(b*L_ + l0 + row)*160 + DTRANK + c];
    }
    float negA[DSTATE];
    #pragma unroll
    for(int n=0;n<DSTATE;n++) negA[n] = -expf(A_log[d*DSTATE + n]) * LOG2E;
    const float Dv = Dvec[d];
    float h[DSTATE];
    const size_t o = (size_t)(b*NCHUNK + chunk)*DSTATE*DINNER + d;
    #pragma unroll
    for(int n=0;n<DSTATE;n++) h[n] = sc_h[o + (size_t)n*DINNER];
    __syncthreads();

    size_t idx = (size_t)(b*L_ + l0)*DINNER + d;
    float dt_c = bf2f(dt_bf[idx]);
    float xv_c = bf2f(xconv[idx]);
    float zv_c = bf2f(z_bf[idx]);
    for(int l=0;l<CLEN;l++){
        float dt_n = 0.f, xv_n = 0.f, zv_n = 0.f;
        if (l+1 < CLEN){
            dt_n = bf2f(dt_bf[idx + DINNER]);
            xv_n = bf2f(xconv[idx + DINNER]);
            zv_n = bf2f(z_bf[idx + DINNER]);
        }
        const float dx = dt_c * xv_c;
        float y = 0.f;
        #pragma unroll
        for(int n=0;n<DSTATE;n++){
            const float t = dt_c * negA[n];
            h[n] = fmaf(h[n], fast_exp2(t), dx*BCs[l][n]);
            y = fmaf(h[n], BCs[l][DSTATE+n], y);
        }
        const float g = zv_c * sigmoidf_(zv_c);
        y_bf[idx] = f2bf(fmaf(xv_c, Dv, y) * g);
        dt_c = dt_n; xv_c = xv_n; zv_c = zv_n;
        idx += DINNER;
    }
}

extern "C" void kernel_launch(void* const* d_in, const int* in_sizes, int n_in,
                              void* d_out, int out_size, void* d_ws, size_t ws_size,
                              hipStream_t stream) {
    const float* hs      = (const float*)d_in[0];
    const float* w_in    = (const float*)d_in[1];
    const float* w_conv  = (const float*)d_in[2];
    const float* b_conv  = (const float*)d_in[3];
    const float* w_xproj = (const float*)d_in[4];
    const float* w_dt    = (const float*)d_in[5];
    const float* b_dt    = (const float*)d_in[6];
    const float* w_out   = (const float*)d_in[7];
    const float* A_log   = (const float*)d_in[8];
    const float* Dvec    = (const float*)d_in[9];
    float* out = (float*)d_out;

    // workspace layout (peak 176 MiB):
    // [0,32M)    x_bf -> after conv: xdbl@0, wx_bf@4M, dtlo@6M, wdt@7M, sc_h@8M(16.75M)
    // [32M,64M)  z_bf               (live to phase3)
    // [64M,96M)  xconv              (live to phase3)
    // [96M,128M) wi_bf -> dt_bf (dt_proj) -> y_bf IN-PLACE (phase3) -> out_proj A
    // [128M,144M) hs_bf -> sc_S (phase1..phase2)
    // [144M,176M) xp_par (x_proj partials, dead after reduce) -> wo_bf@144M (16M)
    char* base = (char*)d_ws;
    ushort_t* x_bf   = (ushort_t*)(base);
    float*    xdbl   = (float*)   (base);
    ushort_t* wx_bf  = (ushort_t*)(base + (4u<<20));
    ushort_t* dtlo_bf= (ushort_t*)(base + (6u<<20));
    ushort_t* wdt_bf = (ushort_t*)(base + (7u<<20));
    float*    sc_h   = (float*)   (base + (8u<<20));
    ushort_t* z_bf   = (ushort_t*)(base + (32u<<20));
    ushort_t* xconv  = (ushort_t*)(base + (64u<<20));
    ushort_t* wi_bf  = (ushort_t*)(base + (96u<<20));
    ushort_t* dt_bf  = (ushort_t*)(base + (96u<<20));
    ushort_t* y_bf   = (ushort_t*)(base + (96u<<20));   // in-place over dt_bf
    ushort_t* hs_bf  = (ushort_t*)(base + (128u<<20));
    float*    sc_S   = (float*)   (base + (128u<<20));
    float*    xp_par = (float*)   (base + (144u<<20));  // 8*4096*256*4 = 32 MiB
    ushort_t* wo_bf  = (ushort_t*)(base + (144u<<20));  // 16 MiB, after reduce

    dim3 blk(256);
    dim3 blkW(1024);

    // convert activations + in_proj weights to bf16 (one launch)
    cvt2_bf16<<<dim3((MROWS*DMODEL/4 + 2*DINNER*DMODEL/4)/256), blk, 0, stream>>>(
        hs, hs_bf, MROWS*DMODEL/4, w_in, wi_bf, 2*DINNER*DMODEL/4);

    // fused in_proj (256^2 v7): N=8192, split x / z halves
    gemm_256w<1,1><<<dim3(MROWS/256, 2*DINNER/256), blkW, 0, stream>>>(
        hs_bf, DMODEL, wi_bf, DMODEL, x_bf, z_bf, DINNER, DMODEL);

    // conv + silu -> xconv bf16 (x_bf region becomes free after this)
    conv_silu_bf<<<dim3((size_t)MROWS*DINNER/256), blk, 0, stream>>>(x_bf, w_conv, b_conv, xconv);

    // w_xproj pad-cvt + w_dt cvt (one launch; [0,32M) region free now)
    cvt_xw<<<dim3((262144 + 131072)/256), blk, 0, stream>>>(w_xproj, wx_bf, w_dt, wdt_bf);

    // x_proj: split-K x 8 into f32 partials, then reduce (+fused dtlo cvt)
    gemm_mfma<0,0,0,1><<<dim3(MROWS/128, 2, 8), blk, 0, stream>>>(
        xconv, DINNER, wx_bf, DINNER, xp_par, nullptr, 256, DINNER/8, nullptr);
    reduce_xproj<<<dim3(MROWS), blk, 0, stream>>>(xp_par, xdbl, dtlo_bf);

    // dt_proj + bias + softplus -> dt_bf
    gemm_mfma<1,1,0,0><<<dim3(MROWS/128, DINNER/128), blk, 0, stream>>>(
        dtlo_bf, DTRANK, wdt_bf, DTRANK, dt_bf, nullptr, DINNER, DTRANK, b_dt);

    // chunked selective scan (thread-per-channel, coalesced)
    dim3 sgrid(DINNER/256, NCHUNK, B_);
    scan_phase1<<<sgrid, blk, 0, stream>>>(dt_bf, xconv, xdbl, A_log, sc_h, sc_S);

    // phase2 + w_out cvt in one launch (wo_bf region dead since reduce_xproj)
    scan_phase2_cvt<<<dim3(CVW + B_*DSTATE*DINNER/256), blk, 0, stream>>>(
        sc_h, sc_S, w_out, wo_bf);

    // phase3: y overwrites dt_bf in place
    scan_phase3<<<sgrid, blk, 0, stream>>>(dt_bf, xconv, xdbl, z_bf, A_log, Dvec, sc_h, y_bf);

    // out_proj (128^2 kernel, 512 blocks -> full machine, direct f32 out)
    gemm_mfma<0,0,0,0><<<dim3(MROWS/128, DMODEL/128), blk, 0, stream>>>(
        y_bf, DINNER, wo_bf, DINNER, out, nullptr, DMODEL, DINNER, nullptr);
}